// Round 3
// baseline (2936.208 us; speedup 1.0000x reference)
//
#include <hip/hip_runtime.h>
#include <stdint.h>
#include <stddef.h>

// CharPredictorMultirateFFN on MI355X (gfx950).
// Pipeline: gather(+pad) -> conv_w transpose -> lin_w transpose -> conv GEMM (fp16 MFMA)
//           -> linear GEMM + fused softmax.
// Conv trick: with kk = k*E + e, im2col A is contiguous rows of the padded emb buffer
// (15 zero rows per batch item), so the conv is a plain GEMM M=65536,N=1024,K=8192.
//
// R3: conv GEMM restructured BARRIER-FREE. Both A (embp rows) and B (wt2 [n][32k])
// admit direct per-lane-contiguous 16B fragment loads, so LDS + __syncthreads are
// removed entirely. Register ping-pong double buffer => compiler emits partial
// s_waitcnt vmcnt(8) (hipBLASLt-style pipeline). MFMA shape 32x32x16 (2178 TF
// ceiling, half the issue count). Block swizzle: XCD-pinned groups of
// {m-strip x all 8 n} so A strips stay L2-resident across the 16 tap passes.

typedef _Float16 f16;
typedef __attribute__((ext_vector_type(8))) _Float16 f16x8;
typedef __attribute__((ext_vector_type(4))) float f32x4;
typedef __attribute__((ext_vector_type(16))) float f32x16;

#define SP 2063  // padded rows per batch item: 15 + 2048

__device__ __forceinline__ void gl2lds16(const void* g, void* l) {
  __builtin_amdgcn_global_load_lds((const __attribute__((address_space(1))) void*)g,
                                   (__attribute__((address_space(3))) void*)l, 16, 0, 0);
}

// ---------------- gather: emb_table[seq] -> f16 padded buffer [32][2063][512] --------
__global__ __launch_bounds__(256) void k_gather(const int* __restrict__ seq,
                                                const float* __restrict__ tab,
                                                f16* __restrict__ embp) {
  int row = blockIdx.x * 4 + (threadIdx.x >> 6);   // 0 .. 66015
  int lane = threadIdx.x & 63;
  int b = row / SP;
  int r = row - b * SP;
  f16* dst = embp + (size_t)row * 512 + lane * 8;
  if (r < 15) {
    f16x8 z = {(f16)0, (f16)0, (f16)0, (f16)0, (f16)0, (f16)0, (f16)0, (f16)0};
    *(f16x8*)dst = z;
  } else {
    int idx = seq[b * 2048 + (r - 15)];
    const float4* src = (const float4*)(tab + (size_t)idx * 512 + lane * 8);
    float4 v0 = src[0], v1 = src[1];
    f16x8 o;
    o[0] = (f16)v0.x; o[1] = (f16)v0.y; o[2] = (f16)v0.z; o[3] = (f16)v0.w;
    o[4] = (f16)v1.x; o[5] = (f16)v1.y; o[6] = (f16)v1.z; o[7] = (f16)v1.w;
    *(f16x8*)dst = o;
  }
}

// ---------------- conv_w [H][E][K] f32 -> wt2 [256 kblk][1024 h][32] f16 -------------
// kk = k*512 + e ; kblk = kk>>5 = k*16 + (e>>5) ; inner = e&31
__global__ __launch_bounds__(256) void k_twc(const float* __restrict__ cw,
                                             f16* __restrict__ wt2) {
  int o = blockIdx.x * 256 + threadIdx.x;  // 8388608 outputs
  int e5 = o & 31;
  int h = (o >> 5) & 1023;
  int kb = o >> 15;            // 0..255
  int k = kb >> 4;
  int e = ((kb & 15) << 5) | e5;
  wt2[o] = (f16)cw[(size_t)h * 8192 + e * 16 + k];
}

// ---------------- lin_w [V][F] f32 -> lt2 [48 fblk][256 v][32] f16 -------------------
__global__ __launch_bounds__(256) void k_twl(const float* __restrict__ lw,
                                             f16* __restrict__ lt2) {
  int o = blockIdx.x * 256 + threadIdx.x;  // 393216 outputs
  int f5 = o & 31;
  int v = (o >> 5) & 255;
  int kb = o >> 13;            // 0..47
  int f = (kb << 5) | f5;
  lt2[o] = (f16)lw[(size_t)v * 1536 + f];
}

// ---------------- conv GEMM: [65536 x 8192] x [8192 x 1024] -> relu -> f16 -----------
// Barrier-free, LDS-free: direct global->VGPR fragment loads, register double buffer.
// 32x32x16 MFMA. A-frag: m=lane&31, k=(lane>>5)*8+j. B-frag: n=lane&31, same k.
__global__ __launch_bounds__(256) void k_conv(const f16* __restrict__ embp,
                                              const f16* __restrict__ wt2,
                                              const float* __restrict__ cb,
                                              f16* __restrict__ cout) {
  // XCD-pinned swizzle: bid%8 picks XCD-intent; within it, n varies fastest so an
  // XCD's co-resident blocks = ~10 m-strips x all 8 n (A strips L2-resident).
  int bid = blockIdx.x;
  int x8 = bid & 7;
  int s = bid >> 3;            // 0..511
  int nb = s & 7;              // n-block
  int mb = ((s >> 3) << 3) | x8;  // m-block 0..511
  int n0 = nb << 7, m0 = mb << 7;
  int b = m0 >> 11, t0 = m0 & 2047;
  int tid = threadIdx.x, lane = tid & 63, wave = tid >> 6;
  int wr = wave >> 1, wc = wave & 1;   // wave tile 64x64 within 128x128 block
  int l31 = lane & 31, l5 = lane >> 5;

  // A: physical row b*SP + t0 + wr*64 + mi*32 + l31 ; halves offset kb*32 + ks*16 + l5*8
  const f16* aBase = embp + (size_t)(b * SP + t0 + wr * 64 + l31) * 512 + l5 * 8;
  // B: wt2[kb][n0 + wc*64 + nj*32 + l31][ks*16 + l5*8]
  const f16* bBase = wt2 + (size_t)(n0 + wc * 64 + l31) * 32 + l5 * 8;

  f32x16 acc[2][2];
#pragma unroll
  for (int i = 0; i < 2; ++i)
#pragma unroll
    for (int j = 0; j < 2; ++j)
#pragma unroll
      for (int r = 0; r < 16; ++r) acc[i][j][r] = 0.f;

  f16x8 A0[2][2], B0[2][2], A1[2][2], B1[2][2];

#define LOADF(Af, Bf, kb) do {                                              \
    const f16* ap = aBase + (kb) * 32;                                      \
    const f16* bp = bBase + (size_t)(kb) * 32768;                           \
    Af[0][0] = *(const f16x8*)(ap);                                         \
    Af[0][1] = *(const f16x8*)(ap + 16);                                    \
    Af[1][0] = *(const f16x8*)(ap + 16384);                                 \
    Af[1][1] = *(const f16x8*)(ap + 16400);                                 \
    Bf[0][0] = *(const f16x8*)(bp);                                         \
    Bf[0][1] = *(const f16x8*)(bp + 16);                                    \
    Bf[1][0] = *(const f16x8*)(bp + 1024);                                  \
    Bf[1][1] = *(const f16x8*)(bp + 1040);                                  \
  } while (0)

#define MF(Af, Bf) do {                                                     \
    _Pragma("unroll")                                                       \
    for (int ks = 0; ks < 2; ++ks)                                          \
      _Pragma("unroll")                                                     \
      for (int mi = 0; mi < 2; ++mi)                                        \
        _Pragma("unroll")                                                   \
        for (int nj = 0; nj < 2; ++nj)                                      \
          acc[mi][nj] = __builtin_amdgcn_mfma_f32_32x32x16_f16(             \
              Af[mi][ks], Bf[nj][ks], acc[mi][nj], 0, 0, 0);                \
  } while (0)

  LOADF(A0, B0, 0);
  for (int kb = 0; kb < 254; kb += 2) {
    LOADF(A1, B1, kb + 1);
    MF(A0, B0);
    LOADF(A0, B0, kb + 2);
    MF(A1, B1);
  }
  LOADF(A1, B1, 255);
  MF(A0, B0);
  MF(A1, B1);
#undef LOADF
#undef MF

  // epilogue: bias + relu + f16 store.
  // 32x32 C/D: col = lane&31, row = (reg&3) + 8*(reg>>2) + 4*(lane>>5)
#pragma unroll
  for (int nj = 0; nj < 2; ++nj) {
    int h = n0 + wc * 64 + nj * 32 + l31;
    float bias = cb[h];
#pragma unroll
    for (int mi = 0; mi < 2; ++mi) {
      int mb2 = m0 + wr * 64 + mi * 32 + 4 * l5;
#pragma unroll
      for (int rg = 0; rg < 16; ++rg) {
        int m = mb2 + (rg & 3) + 8 * (rg >> 2);
        float v = acc[mi][nj][rg] + bias;
        v = v > 0.f ? v : 0.f;
        cout[(size_t)m * 1024 + h] = (f16)v;
      }
    }
  }
}

// ---------------- linear GEMM [65536 x 1536] x [1536 x 256] + fused softmax ----------
__global__ __launch_bounds__(256) void k_lin(const f16* __restrict__ embp,
                                             const f16* __restrict__ cout,
                                             const f16* __restrict__ lt2,
                                             const float* __restrict__ lb,
                                             float* __restrict__ out) {
  __shared__ __align__(16) char smem[32 * 261 * 4];  // Ls overlays As|Bs
  __shared__ float pmax[4][32], psum[4][32], mrow[32], rinv[32];
  f16* As = (f16*)smem;             // [64][32]   4 KB
  f16* Bs = (f16*)(smem + 4096);    // [256][32] 16 KB
  float* Ls = (float*)smem;         // [32][261] f32 epilogue logits
  int m0 = blockIdx.x << 6;
  int b = m0 >> 11, t0 = m0 & 2047;
  int tid = threadIdx.x, lane = tid & 63, wave = tid >> 6;
  int sr = lane >> 2, sc = (lane & 3) << 3;
  const f16* gAe = embp + (size_t)(b * SP + 15 + t0 + wave * 16 + sr) * 512 + sc;
  const f16* gAc = cout + (size_t)(m0 + wave * 16 + sr) * 1024 + sc;
  f16* lA = As + wave * 512;
  int fr = lane & 15, fq = (lane >> 4) << 3;
  f32x4 zero = {0.f, 0.f, 0.f, 0.f};
  f32x4 acc[4][4];
#pragma unroll
  for (int i = 0; i < 4; ++i)
#pragma unroll
    for (int j = 0; j < 4; ++j) acc[i][j] = zero;

  for (int kb = 0; kb < 48; ++kb) {
    if (kb < 16) gl2lds16(gAe + kb * 32, lA);
    else         gl2lds16(gAc + (kb - 16) * 32, lA);
#pragma unroll
    for (int jj = 0; jj < 4; ++jj) {
      int c = wave * 4 + jj;
      gl2lds16(lt2 + (size_t)kb * 8192 + (c * 16 + sr) * 32 + sc, Bs + c * 512);
    }
    __syncthreads();
    f16x8 af[4], bf[4];
#pragma unroll
    for (int i = 0; i < 4; ++i)
      af[i] = *(const f16x8*)(As + (i * 16 + fr) * 32 + fq);
#pragma unroll
    for (int j = 0; j < 4; ++j)
      bf[j] = *(const f16x8*)(Bs + (wave * 64 + j * 16 + fr) * 32 + fq);
#pragma unroll
    for (int i = 0; i < 4; ++i)
#pragma unroll
      for (int j = 0; j < 4; ++j)
        acc[i][j] = __builtin_amdgcn_mfma_f32_16x16x32_f16(af[i], bf[j], acc[i][j], 0, 0, 0);
    __syncthreads();
  }

  // softmax epilogue, two 32-row halves (keeps LDS small). Ls stride 261 avoids
  // 8-way bank conflicts on the per-row column scans (261%32=5, coprime with 32).
  int col = lane & 15, rq = (lane >> 4) << 2;
  for (int hf = 0; hf < 2; ++hf) {
    __syncthreads();
#pragma unroll
    for (int j = 0; j < 4; ++j) {
      int v = wave * 64 + j * 16 + col;
      float bias = lb[v];
#pragma unroll
      for (int i = 0; i < 2; ++i) {
        int rloc = i * 16 + rq;
        int ig = hf * 2 + i;
#pragma unroll
        for (int rg = 0; rg < 4; ++rg)
          Ls[(rloc + rg) * 261 + v] = acc[ig][j][rg] + bias;
      }
    }
    __syncthreads();
    if (tid < 128) {
      int r = tid & 31, q = tid >> 5;
      const float* rowp = Ls + r * 261 + q * 64;
      float pm = -1e30f;
#pragma unroll 8
      for (int c = 0; c < 64; ++c) pm = fmaxf(pm, rowp[c]);
      pmax[q][r] = pm;
    }
    __syncthreads();
    if (tid < 32)
      mrow[tid] = fmaxf(fmaxf(pmax[0][tid], pmax[1][tid]), fmaxf(pmax[2][tid], pmax[3][tid]));
    __syncthreads();
    if (tid < 128) {
      int r = tid & 31, q = tid >> 5;
      const float* rowp = Ls + r * 261 + q * 64;
      float mr = mrow[r], ps = 0.f;
#pragma unroll 8
      for (int c = 0; c < 64; ++c) ps += __expf(rowp[c] - mr);
      psum[q][r] = ps;
    }
    __syncthreads();
    if (tid < 32)
      rinv[tid] = 1.f / (psum[0][tid] + psum[1][tid] + psum[2][tid] + psum[3][tid]);
    __syncthreads();
    float* obase = out + (size_t)(m0 + hf * 32) * 256 + tid;
#pragma unroll 4
    for (int r = 0; r < 32; ++r)
      obase[(size_t)r * 256] = __expf(Ls[r * 261 + tid] - mrow[r]) * rinv[r];
  }
}

extern "C" void kernel_launch(void* const* d_in, const int* in_sizes, int n_in,
                              void* d_out, int out_size, void* d_ws, size_t ws_size,
                              hipStream_t stream) {
  const int*   seq = (const int*)d_in[0];
  const float* tab = (const float*)d_in[1];
  const float* cw  = (const float*)d_in[2];
  const float* cb  = (const float*)d_in[3];
  const float* lw  = (const float*)d_in[4];
  const float* lb  = (const float*)d_in[5];
  float* out = (float*)d_out;
  char* ws = (char*)d_ws;
  // workspace layout (needs ~219.4 MB):
  f16* embp = (f16*)(ws);               //  67,600,384 B  [32*2063][512]
  f16* cout = (f16*)(ws + 67600384);    // 134,217,728 B  [65536][1024]
  f16* wt2  = (f16*)(ws + 201818112);   //  16,777,216 B  [256][1024][32]
  f16* lt2  = (f16*)(ws + 218595328);   //     786,432 B  [48][256][32]

  hipLaunchKernelGGL(k_gather, dim3(16504), dim3(256), 0, stream, seq, tab, embp);
  hipLaunchKernelGGL(k_twc,    dim3(32768), dim3(256), 0, stream, cw, wt2);
  hipLaunchKernelGGL(k_twl,    dim3(1536),  dim3(256), 0, stream, lw, lt2);
  hipLaunchKernelGGL(k_conv,   dim3(4096), dim3(256), 0, stream, embp, wt2, cb, cout);
  hipLaunchKernelGGL(k_lin,    dim3(1024),  dim3(256), 0, stream, embp, cout, lt2, lb, out);
}

// Round 4
// 1548.156 us; speedup vs baseline: 1.8966x; 1.8966x over previous
//
#include <hip/hip_runtime.h>
#include <stdint.h>
#include <stddef.h>

// CharPredictorMultirateFFN on MI355X (gfx950).
// Pipeline: gather(+pad) -> conv_w transpose -> lin_w transpose -> conv GEMM (fp16 MFMA)
//           -> linear GEMM + fused softmax.
// Conv trick: with kk = k*E + e, im2col A is contiguous rows of the padded emb buffer
// (15 zero rows per batch item), so the conv is a plain GEMM M=65536,N=1024,K=8192.
//
// R4: revert to R2's LDS-staged 2-barrier structure (R3's LDS-free version was
// L1-return-BW bound: MfmaUtil 15.9%, nothing busy). Changes vs R2:
//  - MFMA 32x32x16 (8.07 cyc/32k FLOP vs 4.85/16k: ~15% less MFMA-pipe time;
//    fragment+epilogue mapping verified end-to-end in R3).
//  - BK=64 (LDS 2x32KB): halves the count of vmcnt(0)-drain barriers (the
//    structural ~20% stall of this K-loop shape).
//  - XOR swizzle generalized: phys_chunk = logical ^ (row&7) -> every 16-lane
//    ds_read_b128 phase is exactly 2-way bank-aliased = free (m136).
//  - wt2 re-laid out [128 kb2][1024 h][64] so B rows are 64-half contiguous.
//  - grid (512 m, 8 n), m fastest: lower HBM fetch (mattered not at 1.3ms, will at ~1ms).

typedef _Float16 f16;
typedef __attribute__((ext_vector_type(8))) _Float16 f16x8;
typedef __attribute__((ext_vector_type(4))) float f32x4;
typedef __attribute__((ext_vector_type(16))) float f32x16;

#define SP 2063  // padded rows per batch item: 15 + 2048

__device__ __forceinline__ void gl2lds16(const void* g, void* l) {
  __builtin_amdgcn_global_load_lds((const __attribute__((address_space(1))) void*)g,
                                   (__attribute__((address_space(3))) void*)l, 16, 0, 0);
}

// ---------------- gather: emb_table[seq] -> f16 padded buffer [32][2063][512] --------
__global__ __launch_bounds__(256) void k_gather(const int* __restrict__ seq,
                                                const float* __restrict__ tab,
                                                f16* __restrict__ embp) {
  int row = blockIdx.x * 4 + (threadIdx.x >> 6);   // 0 .. 66015
  int lane = threadIdx.x & 63;
  int b = row / SP;
  int r = row - b * SP;
  f16* dst = embp + (size_t)row * 512 + lane * 8;
  if (r < 15) {
    f16x8 z = {(f16)0, (f16)0, (f16)0, (f16)0, (f16)0, (f16)0, (f16)0, (f16)0};
    *(f16x8*)dst = z;
  } else {
    int idx = seq[b * 2048 + (r - 15)];
    const float4* src = (const float4*)(tab + (size_t)idx * 512 + lane * 8);
    float4 v0 = src[0], v1 = src[1];
    f16x8 o;
    o[0] = (f16)v0.x; o[1] = (f16)v0.y; o[2] = (f16)v0.z; o[3] = (f16)v0.w;
    o[4] = (f16)v1.x; o[5] = (f16)v1.y; o[6] = (f16)v1.z; o[7] = (f16)v1.w;
    *(f16x8*)dst = o;
  }
}

// ---------------- conv_w [H][E][K] f32 -> wt2 [128 kb2][1024 h][64] f16 --------------
// kk = k*512 + e ; kb2 = kk>>6 ; inner = kk&63
__global__ __launch_bounds__(256) void k_twc(const float* __restrict__ cw,
                                             f16* __restrict__ wt2) {
  int o = blockIdx.x * 256 + threadIdx.x;  // 8388608 outputs
  int inner = o & 63;
  int h = (o >> 6) & 1023;
  int kb2 = o >> 16;           // 0..127
  int kk = kb2 * 64 + inner;
  int k = kk >> 9;
  int e = kk & 511;
  wt2[o] = (f16)cw[(size_t)h * 8192 + e * 16 + k];
}

// ---------------- lin_w [V][F] f32 -> lt2 [48 fblk][256 v][32] f16 -------------------
__global__ __launch_bounds__(256) void k_twl(const float* __restrict__ lw,
                                             f16* __restrict__ lt2) {
  int o = blockIdx.x * 256 + threadIdx.x;  // 393216 outputs
  int f5 = o & 31;
  int v = (o >> 5) & 255;
  int kb = o >> 13;            // 0..47
  int f = (kb << 5) | f5;
  lt2[o] = (f16)lw[(size_t)v * 1536 + f];
}

// ---------------- conv GEMM: [65536 x 8192] x [8192 x 1024] -> relu -> f16 -----------
// 128x128 block, 4 waves as 2x2 of 64x64 wave tiles (each 2x2 of 32x32 MFMA tiles).
// BK=64. LDS tiles [128 rows][8 chunks of 16B], phys_chunk = logical ^ (row&7).
__global__ __launch_bounds__(256) void k_conv(const f16* __restrict__ embp,
                                              const f16* __restrict__ wt2,
                                              const float* __restrict__ cb,
                                              f16* __restrict__ cout) {
  __shared__ __align__(16) f16 As[128 * 64];
  __shared__ __align__(16) f16 Bs[128 * 64];
  int m0 = blockIdx.x << 7;           // m fastest (512)
  int n0 = blockIdx.y << 7;           // n outer (8)
  int b = m0 >> 11, t0 = m0 & 2047;
  int tid = threadIdx.x, lane = tid & 63, wave = tid >> 6;
  int l31 = lane & 31, l5 = lane >> 5;
  int wr = wave >> 1, wc = wave & 1;

  // staging: wave w, call c stages rows [c*32 + w*8, +8) x 8 chunks.
  // lane -> (srow = lane>>3, phys chunk = lane&7); logical = phys ^ (row&7) = phys ^ srow.
  int srow = lane >> 3;
  int lchunk = (lane & 7) ^ srow;
  const f16* gA = embp + (size_t)(b * SP + t0 + wave * 8 + srow) * 512 + lchunk * 8;
  const f16* gB = wt2 + (size_t)(n0 + wave * 8 + srow) * 64 + lchunk * 8;
  f16* lA = As + (wave * 8) * 64;     // + c*32*64 per call; lane*8 halves implicit
  f16* lB = Bs + (wave * 8) * 64;

  // fragment read offsets: row r = {wr|wc}*64 + t32*32 + l31 ; r&7 = l31&7
  int fsw = l31 & 7;

  f32x16 acc[2][2];
#pragma unroll
  for (int i = 0; i < 2; ++i)
#pragma unroll
    for (int j = 0; j < 2; ++j)
#pragma unroll
      for (int r = 0; r < 16; ++r) acc[i][j][r] = 0.f;

  for (int t = 0; t < 128; ++t) {
#pragma unroll
    for (int c = 0; c < 4; ++c) {
      gl2lds16(gA + (size_t)c * 16384 + (size_t)t * 64, lA + c * 2048);
      gl2lds16(gB + (size_t)c * 2048 + (size_t)t * 65536, lB + c * 2048);
    }
    __syncthreads();
    f16x8 af[2][4], bf[2][4];
#pragma unroll
    for (int mi = 0; mi < 2; ++mi)
#pragma unroll
      for (int ks = 0; ks < 4; ++ks)
        af[mi][ks] = *(const f16x8*)(As + (wr * 64 + mi * 32 + l31) * 64 +
                                     (((ks * 2 + l5) ^ fsw) << 3));
#pragma unroll
    for (int nj = 0; nj < 2; ++nj)
#pragma unroll
      for (int ks = 0; ks < 4; ++ks)
        bf[nj][ks] = *(const f16x8*)(Bs + (wc * 64 + nj * 32 + l31) * 64 +
                                     (((ks * 2 + l5) ^ fsw) << 3));
#pragma unroll
    for (int ks = 0; ks < 4; ++ks)
#pragma unroll
      for (int mi = 0; mi < 2; ++mi)
#pragma unroll
        for (int nj = 0; nj < 2; ++nj)
          acc[mi][nj] = __builtin_amdgcn_mfma_f32_32x32x16_f16(
              af[mi][ks], bf[nj][ks], acc[mi][nj], 0, 0, 0);
    __syncthreads();
  }

  // epilogue: bias + relu + f16 store (verified in R3).
  // 32x32 C/D: col = lane&31, row = (reg&3) + 8*(reg>>2) + 4*(lane>>5)
#pragma unroll
  for (int nj = 0; nj < 2; ++nj) {
    int h = n0 + wc * 64 + nj * 32 + l31;
    float bias = cb[h];
#pragma unroll
    for (int mi = 0; mi < 2; ++mi) {
      int mb2 = m0 + wr * 64 + mi * 32 + 4 * l5;
#pragma unroll
      for (int rg = 0; rg < 16; ++rg) {
        int m = mb2 + (rg & 3) + 8 * (rg >> 2);
        float v = acc[mi][nj][rg] + bias;
        v = v > 0.f ? v : 0.f;
        cout[(size_t)m * 1024 + h] = (f16)v;
      }
    }
  }
}

// ---------------- linear GEMM [65536 x 1536] x [1536 x 256] + fused softmax ----------
__global__ __launch_bounds__(256) void k_lin(const f16* __restrict__ embp,
                                             const f16* __restrict__ cout,
                                             const f16* __restrict__ lt2,
                                             const float* __restrict__ lb,
                                             float* __restrict__ out) {
  __shared__ __align__(16) char smem[32 * 261 * 4];  // Ls overlays As|Bs
  __shared__ float pmax[4][32], psum[4][32], mrow[32], rinv[32];
  f16* As = (f16*)smem;             // [64][32]   4 KB
  f16* Bs = (f16*)(smem + 4096);    // [256][32] 16 KB
  float* Ls = (float*)smem;         // [32][261] f32 epilogue logits
  int m0 = blockIdx.x << 6;
  int b = m0 >> 11, t0 = m0 & 2047;
  int tid = threadIdx.x, lane = tid & 63, wave = tid >> 6;
  int sr = lane >> 2, sc = (lane & 3) << 3;
  const f16* gAe = embp + (size_t)(b * SP + 15 + t0 + wave * 16 + sr) * 512 + sc;
  const f16* gAc = cout + (size_t)(m0 + wave * 16 + sr) * 1024 + sc;
  f16* lA = As + wave * 512;
  int fr = lane & 15, fq = (lane >> 4) << 3;
  f32x4 zero = {0.f, 0.f, 0.f, 0.f};
  f32x4 acc[4][4];
#pragma unroll
  for (int i = 0; i < 4; ++i)
#pragma unroll
    for (int j = 0; j < 4; ++j) acc[i][j] = zero;

  for (int kb = 0; kb < 48; ++kb) {
    if (kb < 16) gl2lds16(gAe + kb * 32, lA);
    else         gl2lds16(gAc + (kb - 16) * 32, lA);
#pragma unroll
    for (int jj = 0; jj < 4; ++jj) {
      int c = wave * 4 + jj;
      gl2lds16(lt2 + (size_t)kb * 8192 + (c * 16 + sr) * 32 + sc, Bs + c * 512);
    }
    __syncthreads();
    f16x8 af[4], bf[4];
#pragma unroll
    for (int i = 0; i < 4; ++i)
      af[i] = *(const f16x8*)(As + (i * 16 + fr) * 32 + fq);
#pragma unroll
    for (int j = 0; j < 4; ++j)
      bf[j] = *(const f16x8*)(Bs + (wave * 64 + j * 16 + fr) * 32 + fq);
#pragma unroll
    for (int i = 0; i < 4; ++i)
#pragma unroll
      for (int j = 0; j < 4; ++j)
        acc[i][j] = __builtin_amdgcn_mfma_f32_16x16x32_f16(af[i], bf[j], acc[i][j], 0, 0, 0);
    __syncthreads();
  }

  // softmax epilogue, two 32-row halves (keeps LDS small). Ls stride 261 avoids
  // 8-way bank conflicts on the per-row column scans (261%32=5, coprime with 32).
  int col = lane & 15, rq = (lane >> 4) << 2;
  for (int hf = 0; hf < 2; ++hf) {
    __syncthreads();
#pragma unroll
    for (int j = 0; j < 4; ++j) {
      int v = wave * 64 + j * 16 + col;
      float bias = lb[v];
#pragma unroll
      for (int i = 0; i < 2; ++i) {
        int rloc = i * 16 + rq;
        int ig = hf * 2 + i;
#pragma unroll
        for (int rg = 0; rg < 4; ++rg)
          Ls[(rloc + rg) * 261 + v] = acc[ig][j][rg] + bias;
      }
    }
    __syncthreads();
    if (tid < 128) {
      int r = tid & 31, q = tid >> 5;
      const float* rowp = Ls + r * 261 + q * 64;
      float pm = -1e30f;
#pragma unroll 8
      for (int c = 0; c < 64; ++c) pm = fmaxf(pm, rowp[c]);
      pmax[q][r] = pm;
    }
    __syncthreads();
    if (tid < 32)
      mrow[tid] = fmaxf(fmaxf(pmax[0][tid], pmax[1][tid]), fmaxf(pmax[2][tid], pmax[3][tid]));
    __syncthreads();
    if (tid < 128) {
      int r = tid & 31, q = tid >> 5;
      const float* rowp = Ls + r * 261 + q * 64;
      float mr = mrow[r], ps = 0.f;
#pragma unroll 8
      for (int c = 0; c < 64; ++c) ps += __expf(rowp[c] - mr);
      psum[q][r] = ps;
    }
    __syncthreads();
    if (tid < 32)
      rinv[tid] = 1.f / (psum[0][tid] + psum[1][tid] + psum[2][tid] + psum[3][tid]);
    __syncthreads();
    float* obase = out + (size_t)(m0 + hf * 32) * 256 + tid;
#pragma unroll 4
    for (int r = 0; r < 32; ++r)
      obase[(size_t)r * 256] = __expf(Ls[r * 261 + tid] - mrow[r]) * rinv[r];
  }
}

extern "C" void kernel_launch(void* const* d_in, const int* in_sizes, int n_in,
                              void* d_out, int out_size, void* d_ws, size_t ws_size,
                              hipStream_t stream) {
  const int*   seq = (const int*)d_in[0];
  const float* tab = (const float*)d_in[1];
  const float* cw  = (const float*)d_in[2];
  const float* cb  = (const float*)d_in[3];
  const float* lw  = (const float*)d_in[4];
  const float* lb  = (const float*)d_in[5];
  float* out = (float*)d_out;
  char* ws = (char*)d_ws;
  // workspace layout (needs ~219.4 MB):
  f16* embp = (f16*)(ws);               //  67,600,384 B  [32*2063][512]
  f16* cout = (f16*)(ws + 67600384);    // 134,217,728 B  [65536][1024]
  f16* wt2  = (f16*)(ws + 201818112);   //  16,777,216 B  [128][1024][64]
  f16* lt2  = (f16*)(ws + 218595328);   //     786,432 B  [48][256][32]

  hipLaunchKernelGGL(k_gather, dim3(16504), dim3(256), 0, stream, seq, tab, embp);
  hipLaunchKernelGGL(k_twc,    dim3(32768), dim3(256), 0, stream, cw, wt2);
  hipLaunchKernelGGL(k_twl,    dim3(1536),  dim3(256), 0, stream, lw, lt2);
  hipLaunchKernelGGL(k_conv,   dim3(512, 8), dim3(256), 0, stream, embp, wt2, cb, cout);
  hipLaunchKernelGGL(k_lin,    dim3(1024),  dim3(256), 0, stream, embp, cout, lt2, lb, out);
}

// Round 5
// 1325.891 us; speedup vs baseline: 2.2145x; 1.1676x over previous
//
#include <hip/hip_runtime.h>
#include <stdint.h>
#include <stddef.h>

// CharPredictorMultirateFFN on MI355X (gfx950).
// Pipeline: gather(+pad) -> conv_w transpose -> lin_w transpose -> conv GEMM (fp16 MFMA)
//           -> linear GEMM + fused softmax.
//
// R5: conv K-loop restructured as (e-block j outer, tap k inner). The tap-k A tile
// is the tap-(k-1) tile shifted one row, so a 143-row x 32-col A slab staged ONCE
// per e-block serves all 16 taps (12 KB vs 16x8 KB re-staged). Per-iter staging:
// 16 KB -> 8 KB (B only) => half the vmcnt-drain at each barrier. Core = R2's
// verified structure (16x16x32 MFMA, 64B rows, zero-conflict XOR swizzle; slab
// swizzle uses ((k+fr)>>1)&3 since tap offset breaks row%16 alignment).
// Grid = R3's XCD swizzle (FETCH 4.0 -> 1.3 GB, verified). k_twc rewritten as
// coalesced per-h LDS transpose (was ~90us of 64B-strided scalar reads).

typedef _Float16 f16;
typedef __attribute__((ext_vector_type(8))) _Float16 f16x8;
typedef __attribute__((ext_vector_type(4))) float f32x4;

#define SP 2063  // padded rows per batch item: 15 + 2048

__device__ __forceinline__ void gl2lds16(const void* g, void* l) {
  __builtin_amdgcn_global_load_lds((const __attribute__((address_space(1))) void*)g,
                                   (__attribute__((address_space(3))) void*)l, 16, 0, 0);
}

// ---------------- gather: emb_table[seq] -> f16 padded buffer [32][2063][512] --------
__global__ __launch_bounds__(256) void k_gather(const int* __restrict__ seq,
                                                const float* __restrict__ tab,
                                                f16* __restrict__ embp) {
  int row = blockIdx.x * 4 + (threadIdx.x >> 6);   // 0 .. 66015
  int lane = threadIdx.x & 63;
  int b = row / SP;
  int r = row - b * SP;
  f16* dst = embp + (size_t)row * 512 + lane * 8;
  if (r < 15) {
    f16x8 z = {(f16)0, (f16)0, (f16)0, (f16)0, (f16)0, (f16)0, (f16)0, (f16)0};
    *(f16x8*)dst = z;
  } else {
    int idx = seq[b * 2048 + (r - 15)];
    const float4* src = (const float4*)(tab + (size_t)idx * 512 + lane * 8);
    float4 v0 = src[0], v1 = src[1];
    f16x8 o;
    o[0] = (f16)v0.x; o[1] = (f16)v0.y; o[2] = (f16)v0.z; o[3] = (f16)v0.w;
    o[4] = (f16)v1.x; o[5] = (f16)v1.y; o[6] = (f16)v1.z; o[7] = (f16)v1.w;
    *(f16x8*)dst = o;
  }
}

// ---------------- conv_w [H][E][K] f32 -> wt2 [256 jk][1024 h][32 e5] f16 ------------
// jk = j*16 + k ; e = j*32 + e5. Coalesced read of one h-row into LDS, transpose out.
__global__ __launch_bounds__(256) void k_twc(const float* __restrict__ cw,
                                             f16* __restrict__ wt2) {
  __shared__ f16 tile[8192];          // [e][k] in source order (16 KB)
  int h = blockIdx.x;                 // 1024 blocks
  const float4* src = (const float4*)(cw + (size_t)h * 8192);
#pragma unroll
  for (int i = 0; i < 8; ++i) {
    int o = i * 256 + threadIdx.x;    // float4 index, fully coalesced
    float4 v = src[o];
    f16* d = tile + o * 4;
    d[0] = (f16)v.x; d[1] = (f16)v.y; d[2] = (f16)v.z; d[3] = (f16)v.w;
  }
  __syncthreads();
  // thread t = j*16+k writes 32 halves: wt2[(t*1024 + h)*32 + e5] = tile[(j*32+e5)*16 + k]
  int j = threadIdx.x >> 4, k = threadIdx.x & 15;
  f16* dst = wt2 + ((size_t)threadIdx.x * 1024 + h) * 32;
#pragma unroll
  for (int c8 = 0; c8 < 4; ++c8) {
    f16x8 v;
#pragma unroll
    for (int t = 0; t < 8; ++t) v[t] = tile[((j * 32 + c8 * 8 + t) << 4) | k];
    *(f16x8*)(dst + c8 * 8) = v;
  }
}

// ---------------- lin_w [V][F] f32 -> lt2 [48 fblk][256 v][32] f16 -------------------
__global__ __launch_bounds__(256) void k_twl(const float* __restrict__ lw,
                                             f16* __restrict__ lt2) {
  int o = blockIdx.x * 256 + threadIdx.x;  // 393216 outputs
  int f5 = o & 31;
  int v = (o >> 5) & 255;
  int kb = o >> 13;            // 0..47
  int f = (kb << 5) | f5;
  lt2[o] = (f16)lw[(size_t)v * 1536 + f];
}

// ---------------- conv GEMM: [65536 x 8192] x [8192 x 1024] -> relu -> f16 -----------
// 128x128 block, 4 waves (2x2 of 64x64 wave tiles, each 4x4 of 16x16 MFMA tiles).
// j outer (16 e-blocks), k inner (16 taps). A slab [192 rows x 32 halves] staged once
// per j; per tap only the 8 KB B tile is staged.
__global__ __launch_bounds__(256) void k_conv(const f16* __restrict__ embp,
                                              const f16* __restrict__ wt2,
                                              const float* __restrict__ cb,
                                              f16* __restrict__ cout) {
  __shared__ __align__(16) f16 Asl[192 * 32];   // 12 KB A slab
  __shared__ __align__(16) f16 Bs[128 * 32];    //  8 KB B tile
  // XCD-pinned swizzle (R3: FETCH 1.32 GB): bid&7 -> XCD, n fastest within.
  int bid = blockIdx.x;
  int x8 = bid & 7;
  int s = bid >> 3;
  int nb = s & 7;
  int mb = ((s >> 3) << 3) | x8;
  int n0 = nb << 7, m0 = mb << 7;
  int b = m0 >> 11, t0 = m0 & 2047;
  int tid = threadIdx.x, lane = tid & 63, wave = tid >> 6;
  int wr = wave >> 1, wc = wave & 1;
  int fr = lane & 15, q = lane >> 4;
  int prl = lane >> 2, pc = lane & 3;   // staging: row-within-64-group, phys chunk

  // A slab staging (3 calls x 4 KB): phys row pr = c*64 + wave*16 + prl, chunk pc;
  // source fetches logical chunk pc ^ ((pr>>1)&3)  (XOR-swizzled layout).
  const f16* gAs[3];
#pragma unroll
  for (int c = 0; c < 3; ++c) {
    int pr = c * 64 + wave * 16 + prl;
    int clog = pc ^ ((pr >> 1) & 3);
    gAs[c] = embp + (size_t)(b * SP + t0 + pr) * 512 + clog * 8;
  }
  f16* lA0 = Asl + (wave * 16) * 32;            // wave-uniform LDS bases
  // B tile staging (2 calls x 4 KB), same swizzle scheme (R2-verified, 0 conflicts).
  const f16* gBs[2];
#pragma unroll
  for (int c = 0; c < 2; ++c) {
    int pr = c * 64 + wave * 16 + prl;
    int clog = pc ^ ((pr >> 1) & 3);
    gBs[c] = wt2 + (size_t)(n0 + pr) * 32 + clog * 8;
  }
  f16* lB0 = Bs + (wave * 16) * 32;

  int fqB = (q ^ ((fr >> 1) & 3)) << 3;         // B frag phys chunk (rows % 16 aligned)

  f32x4 zero = {0.f, 0.f, 0.f, 0.f};
  f32x4 acc[4][4];
#pragma unroll
  for (int i = 0; i < 4; ++i)
#pragma unroll
    for (int jj = 0; jj < 4; ++jj) acc[i][jj] = zero;

  size_t bAdv = 0;
  for (int j = 0; j < 16; ++j) {
#pragma unroll
    for (int c = 0; c < 3; ++c)                  // A slab for this e-block (once)
      gl2lds16(gAs[c] + j * 32, lA0 + c * 2048);
    for (int k = 0; k < 16; ++k) {
#pragma unroll
      for (int c = 0; c < 2; ++c)                // B tile for (j,k)
        gl2lds16(gBs[c] + bAdv, lB0 + c * 2048);
      bAdv += 32768;
      __syncthreads();
      // A frag: slab row = k + wr*64 + i*16 + fr ; swizzle includes tap offset k.
      int aswz = ((k + fr) >> 1) & 3;
      const f16* ap = Asl + (size_t)(k + wr * 64 + fr) * 32 + ((q ^ aswz) << 3);
      f16x8 af[4], bf[4];
#pragma unroll
      for (int i = 0; i < 4; ++i)
        af[i] = *(const f16x8*)(ap + i * 512);
#pragma unroll
      for (int jj = 0; jj < 4; ++jj)
        bf[jj] = *(const f16x8*)(Bs + (wc * 64 + jj * 16 + fr) * 32 + fqB);
#pragma unroll
      for (int i = 0; i < 4; ++i)
#pragma unroll
        for (int jj = 0; jj < 4; ++jj)
          acc[i][jj] = __builtin_amdgcn_mfma_f32_16x16x32_f16(af[i], bf[jj], acc[i][jj], 0, 0, 0);
      __syncthreads();
    }
  }
  // epilogue: bias + relu + f16 store. C/D: col=lane&15 (n), row=(lane>>4)*4+reg (m)
  int col = lane & 15, rq = (lane >> 4) << 2;
  int mbase = m0 + wr * 64 + rq;
  int nbase = n0 + wc * 64 + col;
#pragma unroll
  for (int jj = 0; jj < 4; ++jj) {
    int h = nbase + jj * 16;
    float bias = cb[h];
#pragma unroll
    for (int i = 0; i < 4; ++i) {
      int m = mbase + i * 16;
#pragma unroll
      for (int rg = 0; rg < 4; ++rg) {
        float v = acc[i][jj][rg] + bias;
        v = v > 0.f ? v : 0.f;
        cout[(size_t)(m + rg) * 1024 + h] = (f16)v;
      }
    }
  }
}

// ---------------- linear GEMM [65536 x 1536] x [1536 x 256] + fused softmax ----------
__global__ __launch_bounds__(256) void k_lin(const f16* __restrict__ embp,
                                             const f16* __restrict__ cout,
                                             const f16* __restrict__ lt2,
                                             const float* __restrict__ lb,
                                             float* __restrict__ out) {
  __shared__ __align__(16) char smem[32 * 261 * 4];  // Ls overlays As|Bs
  __shared__ float pmax[4][32], psum[4][32], mrow[32], rinv[32];
  f16* As = (f16*)smem;             // [64][32]   4 KB
  f16* Bs = (f16*)(smem + 4096);    // [256][32] 16 KB
  float* Ls = (float*)smem;         // [32][261] f32 epilogue logits
  int m0 = blockIdx.x << 6;
  int b = m0 >> 11, t0 = m0 & 2047;
  int tid = threadIdx.x, lane = tid & 63, wave = tid >> 6;
  int sr = lane >> 2, sc = (lane & 3) << 3;
  const f16* gAe = embp + (size_t)(b * SP + 15 + t0 + wave * 16 + sr) * 512 + sc;
  const f16* gAc = cout + (size_t)(m0 + wave * 16 + sr) * 1024 + sc;
  f16* lA = As + wave * 512;
  int fr = lane & 15, fq = (lane >> 4) << 3;
  f32x4 zero = {0.f, 0.f, 0.f, 0.f};
  f32x4 acc[4][4];
#pragma unroll
  for (int i = 0; i < 4; ++i)
#pragma unroll
    for (int j = 0; j < 4; ++j) acc[i][j] = zero;

  for (int kb = 0; kb < 48; ++kb) {
    if (kb < 16) gl2lds16(gAe + kb * 32, lA);
    else         gl2lds16(gAc + (kb - 16) * 32, lA);
#pragma unroll
    for (int jj = 0; jj < 4; ++jj) {
      int c = wave * 4 + jj;
      gl2lds16(lt2 + (size_t)kb * 8192 + (c * 16 + sr) * 32 + sc, Bs + c * 512);
    }
    __syncthreads();
    f16x8 af[4], bf[4];
#pragma unroll
    for (int i = 0; i < 4; ++i)
      af[i] = *(const f16x8*)(As + (i * 16 + fr) * 32 + fq);
#pragma unroll
    for (int j = 0; j < 4; ++j)
      bf[j] = *(const f16x8*)(Bs + (wave * 64 + j * 16 + fr) * 32 + fq);
#pragma unroll
    for (int i = 0; i < 4; ++i)
#pragma unroll
      for (int j = 0; j < 4; ++j)
        acc[i][j] = __builtin_amdgcn_mfma_f32_16x16x32_f16(af[i], bf[j], acc[i][j], 0, 0, 0);
    __syncthreads();
  }

  // softmax epilogue, two 32-row halves. Ls stride 261 (coprime with 32).
  int col = lane & 15, rq = (lane >> 4) << 2;
  for (int hf = 0; hf < 2; ++hf) {
    __syncthreads();
#pragma unroll
    for (int j = 0; j < 4; ++j) {
      int v = wave * 64 + j * 16 + col;
      float bias = lb[v];
#pragma unroll
      for (int i = 0; i < 2; ++i) {
        int rloc = i * 16 + rq;
        int ig = hf * 2 + i;
#pragma unroll
        for (int rg = 0; rg < 4; ++rg)
          Ls[(rloc + rg) * 261 + v] = acc[ig][j][rg] + bias;
      }
    }
    __syncthreads();
    if (tid < 128) {
      int r = tid & 31, qd = tid >> 5;
      const float* rowp = Ls + r * 261 + qd * 64;
      float pm = -1e30f;
#pragma unroll 8
      for (int c = 0; c < 64; ++c) pm = fmaxf(pm, rowp[c]);
      pmax[qd][r] = pm;
    }
    __syncthreads();
    if (tid < 32)
      mrow[tid] = fmaxf(fmaxf(pmax[0][tid], pmax[1][tid]), fmaxf(pmax[2][tid], pmax[3][tid]));
    __syncthreads();
    if (tid < 128) {
      int r = tid & 31, qd = tid >> 5;
      const float* rowp = Ls + r * 261 + qd * 64;
      float mr = mrow[r], ps = 0.f;
#pragma unroll 8
      for (int c = 0; c < 64; ++c) ps += __expf(rowp[c] - mr);
      psum[qd][r] = ps;
    }
    __syncthreads();
    if (tid < 32)
      rinv[tid] = 1.f / (psum[0][tid] + psum[1][tid] + psum[2][tid] + psum[3][tid]);
    __syncthreads();
    float* obase = out + (size_t)(m0 + hf * 32) * 256 + tid;
#pragma unroll 4
    for (int r = 0; r < 32; ++r)
      obase[(size_t)r * 256] = __expf(Ls[r * 261 + tid] - mrow[r]) * rinv[r];
  }
}

extern "C" void kernel_launch(void* const* d_in, const int* in_sizes, int n_in,
                              void* d_out, int out_size, void* d_ws, size_t ws_size,
                              hipStream_t stream) {
  const int*   seq = (const int*)d_in[0];
  const float* tab = (const float*)d_in[1];
  const float* cw  = (const float*)d_in[2];
  const float* cb  = (const float*)d_in[3];
  const float* lw  = (const float*)d_in[4];
  const float* lb  = (const float*)d_in[5];
  float* out = (float*)d_out;
  char* ws = (char*)d_ws;
  // workspace layout (needs ~219.4 MB):
  f16* embp = (f16*)(ws);               //  67,600,384 B  [32*2063][512]
  f16* cout = (f16*)(ws + 67600384);    // 134,217,728 B  [65536][1024]
  f16* wt2  = (f16*)(ws + 201818112);   //  16,777,216 B  [256 jk][1024 h][32 e5]
  f16* lt2  = (f16*)(ws + 218595328);   //     786,432 B  [48][256][32]

  hipLaunchKernelGGL(k_gather, dim3(16504), dim3(256), 0, stream, seq, tab, embp);
  hipLaunchKernelGGL(k_twc,    dim3(1024),  dim3(256), 0, stream, cw, wt2);
  hipLaunchKernelGGL(k_twl,    dim3(1536),  dim3(256), 0, stream, lw, lt2);
  hipLaunchKernelGGL(k_conv,   dim3(4096),  dim3(256), 0, stream, embp, wt2, cb, cout);
  hipLaunchKernelGGL(k_lin,    dim3(1024),  dim3(256), 0, stream, embp, cout, lt2, lb, out);
}

// Round 6
// 1150.900 us; speedup vs baseline: 2.5512x; 1.1520x over previous
//
#include <hip/hip_runtime.h>
#include <stdint.h>
#include <stddef.h>

// CharPredictorMultirateFFN on MI355X (gfx950).
// Pipeline: gather(+pad) -> conv_w transpose -> lin_w transpose -> conv GEMM (fp16 MFMA)
//           -> linear GEMM + fused softmax.
//
// R6: batch 4 taps per barrier-pair in the conv K-loop. R5 showed the binding term
// is the per-barrier vmcnt(0) drain (~110 net cyc) vs 78 cyc MFMA per iteration
// (42.5% MfmaUtil == 78/186). Bs -> [4][128][32] (32 KB), barriers 512 -> 128,
// MFMA per drain 78 -> 312 cyc. LDS 44 KB total -> 3 blocks/CU. Everything else
// is R5-verified: A-slab-per-eblock (FETCH 574 MB), XOR swizzle (0 conflicts),
// XCD-pinned grid swizzle, coalesced k_twc.

typedef _Float16 f16;
typedef __attribute__((ext_vector_type(8))) _Float16 f16x8;
typedef __attribute__((ext_vector_type(4))) float f32x4;

#define SP 2063  // padded rows per batch item: 15 + 2048

__device__ __forceinline__ void gl2lds16(const void* g, void* l) {
  __builtin_amdgcn_global_load_lds((const __attribute__((address_space(1))) void*)g,
                                   (__attribute__((address_space(3))) void*)l, 16, 0, 0);
}

// ---------------- gather: emb_table[seq] -> f16 padded buffer [32][2063][512] --------
__global__ __launch_bounds__(256) void k_gather(const int* __restrict__ seq,
                                                const float* __restrict__ tab,
                                                f16* __restrict__ embp) {
  int row = blockIdx.x * 4 + (threadIdx.x >> 6);   // 0 .. 66015
  int lane = threadIdx.x & 63;
  int b = row / SP;
  int r = row - b * SP;
  f16* dst = embp + (size_t)row * 512 + lane * 8;
  if (r < 15) {
    f16x8 z = {(f16)0, (f16)0, (f16)0, (f16)0, (f16)0, (f16)0, (f16)0, (f16)0};
    *(f16x8*)dst = z;
  } else {
    int idx = seq[b * 2048 + (r - 15)];
    const float4* src = (const float4*)(tab + (size_t)idx * 512 + lane * 8);
    float4 v0 = src[0], v1 = src[1];
    f16x8 o;
    o[0] = (f16)v0.x; o[1] = (f16)v0.y; o[2] = (f16)v0.z; o[3] = (f16)v0.w;
    o[4] = (f16)v1.x; o[5] = (f16)v1.y; o[6] = (f16)v1.z; o[7] = (f16)v1.w;
    *(f16x8*)dst = o;
  }
}

// ---------------- conv_w [H][E][K] f32 -> wt2 [256 jk][1024 h][32 e5] f16 ------------
// jk = j*16 + k ; e = j*32 + e5. Coalesced read of one h-row into LDS, transpose out.
__global__ __launch_bounds__(256) void k_twc(const float* __restrict__ cw,
                                             f16* __restrict__ wt2) {
  __shared__ f16 tile[8192];          // [e][k] in source order (16 KB)
  int h = blockIdx.x;                 // 1024 blocks
  const float4* src = (const float4*)(cw + (size_t)h * 8192);
#pragma unroll
  for (int i = 0; i < 8; ++i) {
    int o = i * 256 + threadIdx.x;    // float4 index, fully coalesced
    float4 v = src[o];
    f16* d = tile + o * 4;
    d[0] = (f16)v.x; d[1] = (f16)v.y; d[2] = (f16)v.z; d[3] = (f16)v.w;
  }
  __syncthreads();
  // thread t = j*16+k writes 32 halves: wt2[(t*1024 + h)*32 + e5] = tile[(j*32+e5)*16 + k]
  int j = threadIdx.x >> 4, k = threadIdx.x & 15;
  f16* dst = wt2 + ((size_t)threadIdx.x * 1024 + h) * 32;
#pragma unroll
  for (int c8 = 0; c8 < 4; ++c8) {
    f16x8 v;
#pragma unroll
    for (int t = 0; t < 8; ++t) v[t] = tile[((j * 32 + c8 * 8 + t) << 4) | k];
    *(f16x8*)(dst + c8 * 8) = v;
  }
}

// ---------------- lin_w [V][F] f32 -> lt2 [48 fblk][256 v][32] f16 -------------------
__global__ __launch_bounds__(256) void k_twl(const float* __restrict__ lw,
                                             f16* __restrict__ lt2) {
  int o = blockIdx.x * 256 + threadIdx.x;  // 393216 outputs
  int f5 = o & 31;
  int v = (o >> 5) & 255;
  int kb = o >> 13;            // 0..47
  int f = (kb << 5) | f5;
  lt2[o] = (f16)lw[(size_t)v * 1536 + f];
}

// ---------------- conv GEMM: [65536 x 8192] x [8192 x 1024] -> relu -> f16 -----------
// 128x128 block, 4 waves (2x2 of 64x64 wave tiles, each 4x4 of 16x16 MFMA tiles).
// j outer (16 e-blocks), tap-group inner (4 groups of 4 taps). A slab staged once per
// j; per group 4 B tiles staged, one barrier-pair, 64 MFMA per wave per drain.
__global__ __launch_bounds__(256) void k_conv(const f16* __restrict__ embp,
                                              const f16* __restrict__ wt2,
                                              const float* __restrict__ cb,
                                              f16* __restrict__ cout) {
  __shared__ __align__(16) f16 Asl[192 * 32];     // 12 KB A slab
  __shared__ __align__(16) f16 Bs[4 * 128 * 32];  // 32 KB: 4 B tiles
  // XCD-pinned swizzle (R3/R5-verified): bid&7 -> XCD, n fastest within.
  int bid = blockIdx.x;
  int x8 = bid & 7;
  int s = bid >> 3;
  int nb = s & 7;
  int mb = ((s >> 3) << 3) | x8;
  int n0 = nb << 7, m0 = mb << 7;
  int b = m0 >> 11, t0 = m0 & 2047;
  int tid = threadIdx.x, lane = tid & 63, wave = tid >> 6;
  int wr = wave >> 1, wc = wave & 1;
  int fr = lane & 15, q = lane >> 4;
  int prl = lane >> 2, pc = lane & 3;   // staging: row-within-64-group, phys chunk

  // A slab staging (3 calls x 4 KB): phys row pr = c*64 + wave*16 + prl, chunk pc;
  // source fetches logical chunk pc ^ ((pr>>1)&3)  (XOR-swizzled layout).
  const f16* gAs[3];
#pragma unroll
  for (int c = 0; c < 3; ++c) {
    int pr = c * 64 + wave * 16 + prl;
    int clog = pc ^ ((pr >> 1) & 3);
    gAs[c] = embp + (size_t)(b * SP + t0 + pr) * 512 + clog * 8;
  }
  f16* lA0 = Asl + (wave * 16) * 32;            // wave-uniform LDS bases
  // B tile staging (2 calls x 4 KB per tile), same swizzle (R2/R5-verified, 0 conflicts).
  const f16* gBs[2];
#pragma unroll
  for (int c = 0; c < 2; ++c) {
    int pr = c * 64 + wave * 16 + prl;
    int clog = pc ^ ((pr >> 1) & 3);
    gBs[c] = wt2 + (size_t)(n0 + pr) * 32 + clog * 8;
  }
  f16* lB0 = Bs + (wave * 16) * 32;

  int fqB = (q ^ ((fr >> 1) & 3)) << 3;         // B frag phys chunk (rows % 16 aligned)

  f32x4 zero = {0.f, 0.f, 0.f, 0.f};
  f32x4 acc[4][4];
#pragma unroll
  for (int i = 0; i < 4; ++i)
#pragma unroll
    for (int jj = 0; jj < 4; ++jj) acc[i][jj] = zero;

  for (int j = 0; j < 16; ++j) {
#pragma unroll
    for (int c = 0; c < 3; ++c)                  // A slab for this e-block (once per j)
      gl2lds16(gAs[c] + j * 32, lA0 + c * 2048);
    for (int g = 0; g < 4; ++g) {
      // stage 4 B tiles (taps g*4 .. g*4+3)
#pragma unroll
      for (int t = 0; t < 4; ++t) {
        size_t bOff = ((size_t)(j * 16 + g * 4 + t)) * 32768;
#pragma unroll
        for (int c = 0; c < 2; ++c)
          gl2lds16(gBs[c] + bOff, lB0 + t * 4096 + c * 2048);
      }
      __syncthreads();
#pragma unroll 2
      for (int t = 0; t < 4; ++t) {
        int k = g * 4 + t;
        // A frag: slab row = k + wr*64 + i*16 + fr ; swizzle includes tap offset k.
        int aswz = ((k + fr) >> 1) & 3;
        const f16* ap = Asl + (size_t)(k + wr * 64 + fr) * 32 + ((q ^ aswz) << 3);
        f16x8 af[4], bf[4];
#pragma unroll
        for (int i = 0; i < 4; ++i)
          af[i] = *(const f16x8*)(ap + i * 512);
#pragma unroll
        for (int jj = 0; jj < 4; ++jj)
          bf[jj] = *(const f16x8*)(Bs + t * 4096 + (wc * 64 + jj * 16 + fr) * 32 + fqB);
#pragma unroll
        for (int i = 0; i < 4; ++i)
#pragma unroll
          for (int jj = 0; jj < 4; ++jj)
            acc[i][jj] = __builtin_amdgcn_mfma_f32_16x16x32_f16(af[i], bf[jj], acc[i][jj], 0, 0, 0);
      }
      __syncthreads();
    }
  }
  // epilogue: bias + relu + f16 store. C/D: col=lane&15 (n), row=(lane>>4)*4+reg (m)
  int col = lane & 15, rq = (lane >> 4) << 2;
  int mbase = m0 + wr * 64 + rq;
  int nbase = n0 + wc * 64 + col;
#pragma unroll
  for (int jj = 0; jj < 4; ++jj) {
    int h = nbase + jj * 16;
    float bias = cb[h];
#pragma unroll
    for (int i = 0; i < 4; ++i) {
      int m = mbase + i * 16;
#pragma unroll
      for (int rg = 0; rg < 4; ++rg) {
        float v = acc[i][jj][rg] + bias;
        v = v > 0.f ? v : 0.f;
        cout[(size_t)(m + rg) * 1024 + h] = (f16)v;
      }
    }
  }
}

// ---------------- linear GEMM [65536 x 1536] x [1536 x 256] + fused softmax ----------
__global__ __launch_bounds__(256) void k_lin(const f16* __restrict__ embp,
                                             const f16* __restrict__ cout,
                                             const f16* __restrict__ lt2,
                                             const float* __restrict__ lb,
                                             float* __restrict__ out) {
  __shared__ __align__(16) char smem[32 * 261 * 4];  // Ls overlays As|Bs
  __shared__ float pmax[4][32], psum[4][32], mrow[32], rinv[32];
  f16* As = (f16*)smem;             // [64][32]   4 KB
  f16* Bs = (f16*)(smem + 4096);    // [256][32] 16 KB
  float* Ls = (float*)smem;         // [32][261] f32 epilogue logits
  int m0 = blockIdx.x << 6;
  int b = m0 >> 11, t0 = m0 & 2047;
  int tid = threadIdx.x, lane = tid & 63, wave = tid >> 6;
  int sr = lane >> 2, sc = (lane & 3) << 3;
  const f16* gAe = embp + (size_t)(b * SP + 15 + t0 + wave * 16 + sr) * 512 + sc;
  const f16* gAc = cout + (size_t)(m0 + wave * 16 + sr) * 1024 + sc;
  f16* lA = As + wave * 512;
  int fr = lane & 15, fq = (lane >> 4) << 3;
  f32x4 zero = {0.f, 0.f, 0.f, 0.f};
  f32x4 acc[4][4];
#pragma unroll
  for (int i = 0; i < 4; ++i)
#pragma unroll
    for (int j = 0; j < 4; ++j) acc[i][j] = zero;

  for (int kb = 0; kb < 48; ++kb) {
    if (kb < 16) gl2lds16(gAe + kb * 32, lA);
    else         gl2lds16(gAc + (kb - 16) * 32, lA);
#pragma unroll
    for (int jj = 0; jj < 4; ++jj) {
      int c = wave * 4 + jj;
      gl2lds16(lt2 + (size_t)kb * 8192 + (c * 16 + sr) * 32 + sc, Bs + c * 512);
    }
    __syncthreads();
    f16x8 af[4], bf[4];
#pragma unroll
    for (int i = 0; i < 4; ++i)
      af[i] = *(const f16x8*)(As + (i * 16 + fr) * 32 + fq);
#pragma unroll
    for (int j = 0; j < 4; ++j)
      bf[j] = *(const f16x8*)(Bs + (wave * 64 + j * 16 + fr) * 32 + fq);
#pragma unroll
    for (int i = 0; i < 4; ++i)
#pragma unroll
      for (int j = 0; j < 4; ++j)
        acc[i][j] = __builtin_amdgcn_mfma_f32_16x16x32_f16(af[i], bf[j], acc[i][j], 0, 0, 0);
    __syncthreads();
  }

  // softmax epilogue, two 32-row halves. Ls stride 261 (coprime with 32).
  int col = lane & 15, rq = (lane >> 4) << 2;
  for (int hf = 0; hf < 2; ++hf) {
    __syncthreads();
#pragma unroll
    for (int j = 0; j < 4; ++j) {
      int v = wave * 64 + j * 16 + col;
      float bias = lb[v];
#pragma unroll
      for (int i = 0; i < 2; ++i) {
        int rloc = i * 16 + rq;
        int ig = hf * 2 + i;
#pragma unroll
        for (int rg = 0; rg < 4; ++rg)
          Ls[(rloc + rg) * 261 + v] = acc[ig][j][rg] + bias;
      }
    }
    __syncthreads();
    if (tid < 128) {
      int r = tid & 31, qd = tid >> 5;
      const float* rowp = Ls + r * 261 + qd * 64;
      float pm = -1e30f;
#pragma unroll 8
      for (int c = 0; c < 64; ++c) pm = fmaxf(pm, rowp[c]);
      pmax[qd][r] = pm;
    }
    __syncthreads();
    if (tid < 32)
      mrow[tid] = fmaxf(fmaxf(pmax[0][tid], pmax[1][tid]), fmaxf(pmax[2][tid], pmax[3][tid]));
    __syncthreads();
    if (tid < 128) {
      int r = tid & 31, qd = tid >> 5;
      const float* rowp = Ls + r * 261 + qd * 64;
      float mr = mrow[r], ps = 0.f;
#pragma unroll 8
      for (int c = 0; c < 64; ++c) ps += __expf(rowp[c] - mr);
      psum[qd][r] = ps;
    }
    __syncthreads();
    if (tid < 32)
      rinv[tid] = 1.f / (psum[0][tid] + psum[1][tid] + psum[2][tid] + psum[3][tid]);
    __syncthreads();
    float* obase = out + (size_t)(m0 + hf * 32) * 256 + tid;
#pragma unroll 4
    for (int r = 0; r < 32; ++r)
      obase[(size_t)r * 256] = __expf(Ls[r * 261 + tid] - mrow[r]) * rinv[r];
  }
}

extern "C" void kernel_launch(void* const* d_in, const int* in_sizes, int n_in,
                              void* d_out, int out_size, void* d_ws, size_t ws_size,
                              hipStream_t stream) {
  const int*   seq = (const int*)d_in[0];
  const float* tab = (const float*)d_in[1];
  const float* cw  = (const float*)d_in[2];
  const float* cb  = (const float*)d_in[3];
  const float* lw  = (const float*)d_in[4];
  const float* lb  = (const float*)d_in[5];
  float* out = (float*)d_out;
  char* ws = (char*)d_ws;
  // workspace layout (needs ~219.4 MB):
  f16* embp = (f16*)(ws);               //  67,600,384 B  [32*2063][512]
  f16* cout = (f16*)(ws + 67600384);    // 134,217,728 B  [65536][1024]
  f16* wt2  = (f16*)(ws + 201818112);   //  16,777,216 B  [256 jk][1024 h][32 e5]
  f16* lt2  = (f16*)(ws + 218595328);   //     786,432 B  [48][256][32]

  hipLaunchKernelGGL(k_gather, dim3(16504), dim3(256), 0, stream, seq, tab, embp);
  hipLaunchKernelGGL(k_twc,    dim3(1024),  dim3(256), 0, stream, cw, wt2);
  hipLaunchKernelGGL(k_twl,    dim3(1536),  dim3(256), 0, stream, lw, lt2);
  hipLaunchKernelGGL(k_conv,   dim3(4096),  dim3(256), 0, stream, embp, wt2, cb, cout);
  hipLaunchKernelGGL(k_lin,    dim3(1024),  dim3(256), 0, stream, embp, cout, lt2, lb, out);
}